// Round 8
// baseline (321.157 us; speedup 1.0000x reference)
//
#include <hip/hip_runtime.h>
#include <hip/hip_bf16.h>
#include <math.h>

// Problem constants
#define T_ 4
#define N_ 16
#define F_ 6
#define L_ 1024
#define A_ 21
#define K_ 20
#define U_ 256
#define LOUT 1005            // L - K + 1
#define NIMG 384             // T*N*F
#define SZ_S (T_*N_*U_)      // 16384
#define SZ_R (K_*A_*U_)      // 107520

// Packed-X geometry: row stride 24 shorts (48 B). For output row l, contraction
// slot c maps to tap=c/24, col=c%24 (independent of l) -> contiguous aligned
// K-window of 512 slots (16 MFMA K-steps of 32). Cols 21..23 and tap>=20 are
// zero on the R side.
#define XPR 24               // shorts per packed row
#define XROWS 1056           // padded rows per image
#define NSTEP 16             // K-steps of 32 slots (512 >= 19*24+20+1)
#define RT_SHORTS (NSTEP * U_ * 32)   // 131072 shorts = 256 KB

typedef __attribute__((ext_vector_type(8))) short short8;   // 8 bf16 (4 VGPR)
typedef __attribute__((ext_vector_type(4))) float f32x4;    // 4 f32 acc

__device__ __forceinline__ unsigned short f2bf(float f) {
  unsigned int u = __float_as_uint(f);
  u += 0x7FFFu + ((u >> 16) & 1u);   // round to nearest even
  return (unsigned short)(u >> 16);
}

__device__ __forceinline__ void atomicMaxF(float* addr, float val) {
  if (val >= 0.f) atomicMax((int*)addr, __float_as_int(val));
  else            atomicMin((unsigned int*)addr, __float_as_uint(val));
}

// Async global->LDS, 16B per lane. LDS dest is wave-uniform base + lane*16.
__device__ __forceinline__ void gload_lds16(const void* g, void* l) {
  __builtin_amdgcn_global_load_lds(
      (const __attribute__((address_space(1))) void*)g,
      (__attribute__((address_space(3))) void*)l, 16, 0, 0);
}

// S init to -inf, R (fp32, exact) into d_out, and Rt = bf16 R scattered into
// slot order: Rt[(s>>5)*8192 + u*32 + (s&31)], s = k*24 + a. Pad slots are
// zeroed beforehand by hipMemsetAsync.
__global__ void prep_kernel(const float* __restrict__ P_logit,
                            const float* __restrict__ Q,
                            float* __restrict__ out,
                            unsigned short* __restrict__ Rt) {
  int tid = blockIdx.x * blockDim.x + threadIdx.x;
  if (tid < SZ_S) out[tid] = -INFINITY;
  if (tid >= K_ * U_) return;
  int k = tid / U_;
  int u = tid - k * U_;
  const float* pl = P_logit + (size_t)k * A_ * U_ + u;
  float v[A_];
  float m = -INFINITY;
#pragma unroll
  for (int a = 0; a < A_; ++a) { v[a] = pl[(size_t)a * U_]; m = fmaxf(m, v[a]); }
  float s = 0.f;
#pragma unroll
  for (int a = 0; a < A_; ++a) { v[a] = expf(v[a] - m); s += v[a]; }
  float qs = 0.f;
#pragma unroll
  for (int a = 0; a < A_; ++a) qs += Q[a];
  float eps = qs * (1.0f / A_);
  float invs = 1.f / s;
  float* Rout = out + SZ_S;
#pragma unroll
  for (int a = 0; a < A_; ++a) {
    float r = logf(fmaxf(v[a] * invs / Q[a], eps));
    Rout[(size_t)(k * A_ + a) * U_ + u] = r;
    int sl = k * XPR + a;
    Rt[(size_t)(sl >> 5) * (U_ * 32) + u * 32 + (sl & 31)] = f2bf(r);
  }
}

// X (fp32 [n][1024][21]) -> Xp (bf16 [n][1056][24], zero-padded both dims).
__global__ void xconv_kernel(const float* __restrict__ X,
                             unsigned int* __restrict__ Xp32) {
  int t = blockIdx.x * blockDim.x + threadIdx.x;
  if (t >= NIMG * XROWS * 12) return;
  int w  = t % 12;
  int rl = t / 12;                 // n*XROWS + row
  int row = rl % XROWS;
  int n   = rl / XROWS;
  int c0 = w * 2;
  float v0 = 0.f, v1 = 0.f;
  if (row < L_) {
    const float* xr = X + ((size_t)n * L_ + row) * A_;
    if (c0 < A_)     v0 = xr[c0];
    if (c0 + 1 < A_) v1 = xr[c0 + 1];
  }
  unsigned int o = (unsigned int)f2bf(v0) | ((unsigned int)f2bf(v1) << 16);
  Xp32[(size_t)rl * 12 + w] = o;
}

// Conv as one GEMM: M=u (A=R slots), N=l (B=packed-X window), K=512 (16 steps).
// Wave tile RESHAPED vs R5: each wave covers 128u x 32l (8 u-frags x 2
// l-frags, still 16 MFMA/step) -> X ds_reads halved (2/step, LDS pipe now
// under matrix-pipe demand); R frags (8/step) come from global/L2 (VMEM pipe).
// Both operands prefetched one full K-step ahead (static cur/nxt buffers).
// X window (8 KB) staged once via global_load_lds; ONE barrier total.
__global__ __launch_bounds__(256, 3) void conv_kernel(
    const unsigned short* __restrict__ Xp,
    const unsigned short* __restrict__ Rt,
    float* __restrict__ out) {
  __shared__ __align__(16) unsigned short lds_x[4096];   // 8 KB

  const int n  = blockIdx.z;
  const int l0 = blockIdx.y * 128;
  const int u0 = blockIdx.x * 128;
  const int wid  = threadIdx.x >> 6;
  const int lane = threadIdx.x & 63;

  // Stage packed X rows [l0 ..] : 8 x 1KB chunks (2 per wave).
  const char* xsrc = (const char*)Xp + ((size_t)n * XROWS + l0) * (XPR * 2);
#pragma unroll
  for (int r = 0; r < 2; ++r) {
    int c = wid * 2 + r;
    gload_lds16(xsrc + c * 1024 + lane * 16, (char*)lds_x + c * 1024);
  }
  asm volatile("s_waitcnt vmcnt(0)" ::: "memory");
  __syncthreads();

  const int fl = lane & 15;            // frag row (A: u) / col (B: l)
  const int fj = lane >> 4;            // k sub-chunk (8 shorts each)

  f32x4 acc[8][2];                     // [ut][lt]
#pragma unroll
  for (int ut = 0; ut < 8; ++ut)
#pragma unroll
    for (int lt = 0; lt < 2; ++lt)
      acc[ut][lt] = (f32x4){0.f, 0.f, 0.f, 0.f};

  // R frag(step, ut) = rb + step*8192 + ut*512 (shorts); 8 KB/step contiguous,
  // shared by all 4 waves of the block (L2/L1-served).
  const unsigned short* rb = Rt + (size_t)(u0 + fl) * 32 + (fj << 3);
  // X frag(step, lt) = xb + lt*(16*24) + step*32 (shorts, LDS); wave's l-slice
  // is rows wid*32 .. wid*32+31.
  const unsigned short* xb = lds_x + (wid * 32 + fl) * XPR + (fj << 3);

  short8 rcur[8], rnxt[8], xcur[2], xnxt[2];
#pragma unroll
  for (int ut = 0; ut < 8; ++ut)
    rcur[ut] = *(const short8*)(rb + ut * 512);
#pragma unroll
  for (int lt = 0; lt < 2; ++lt)
    xcur[lt] = *(const short8*)(xb + lt * (16 * XPR));

#pragma unroll 1
  for (int s = 0; s < NSTEP; ++s) {
    const int sn = (s + 1 < NSTEP) ? s + 1 : s;   // clamp (last iter discards)
    // issue next-step loads first (one full step of latency cover)
#pragma unroll
    for (int lt = 0; lt < 2; ++lt)
      xnxt[lt] = *(const short8*)(xb + lt * (16 * XPR) + sn * 32);
#pragma unroll
    for (int ut = 0; ut < 8; ++ut)
      rnxt[ut] = *(const short8*)(rb + (size_t)sn * 8192 + ut * 512);
    // 16 MFMA on current step
#pragma unroll
    for (int ut = 0; ut < 8; ++ut)
#pragma unroll
      for (int lt = 0; lt < 2; ++lt)
        acc[ut][lt] = __builtin_amdgcn_mfma_f32_16x16x32_bf16(
            rcur[ut], xcur[lt], acc[ut][lt], 0, 0, 0);
    // rotate
#pragma unroll
    for (int ut = 0; ut < 8; ++ut) rcur[ut] = rnxt[ut];
#pragma unroll
    for (int lt = 0; lt < 2; ++lt) xcur[lt] = xnxt[lt];
  }

  // Epilogue: D layout col(l)=lane&15, row(u)=(lane>>4)*4+reg -> lane holds
  // 4 consecutive u at fixed l => float4 store into row-major Z[l][u].
  float* Z = out + SZ_S + SZ_R;
  const int ug = fj << 2;
  f32x4 pm[8];                         // [ut], max over l
#pragma unroll
  for (int ut = 0; ut < 8; ++ut)
#pragma unroll
    for (int j = 0; j < 4; ++j) pm[ut][j] = -INFINITY;

#pragma unroll
  for (int lt = 0; lt < 2; ++lt) {
    const int l = l0 + wid * 32 + lt * 16 + fl;
    if (l < LOUT) {
      float* zrow = Z + ((size_t)n * LOUT + l) * U_ + u0 + ug;
#pragma unroll
      for (int ut = 0; ut < 8; ++ut) {
        f32x4 v = acc[ut][lt];
        *(f32x4*)(zrow + ut * 16) = v;
#pragma unroll
        for (int j = 0; j < 4; ++j) pm[ut][j] = fmaxf(pm[ut][j], v[j]);
      }
    }
  }

  // Max over the frag's 16 cols (l): xor-reduce over lane&15 (fj preserved).
#pragma unroll
  for (int off = 1; off < 16; off <<= 1)
#pragma unroll
    for (int ut = 0; ut < 8; ++ut)
#pragma unroll
      for (int j = 0; j < 4; ++j)
        pm[ut][j] = fmaxf(pm[ut][j], __shfl_xor(pm[ut][j], off));

  if (fl == 0) {                       // 4 lanes (fj = 0..3)
    const int tn = n / F_;
    float* Sp = out + (size_t)tn * U_ + u0 + ug;
#pragma unroll
    for (int ut = 0; ut < 8; ++ut)
#pragma unroll
      for (int j = 0; j < 4; ++j)
        atomicMaxF(Sp + ut * 16 + j, pm[ut][j]);
  }
}

extern "C" void kernel_launch(void* const* d_in, const int* in_sizes, int n_in,
                              void* d_out, int out_size, void* d_ws, size_t ws_size,
                              hipStream_t stream) {
  const float* X       = (const float*)d_in[0];
  const float* P_logit = (const float*)d_in[1];
  const float* Q       = (const float*)d_in[2];
  float* out = (float*)d_out;

  unsigned short* Rt = (unsigned short*)d_ws;            // 256 KB
  const size_t rt_bytes = (size_t)RT_SHORTS * 2;
  unsigned short* Xp = (unsigned short*)((char*)d_ws + rt_bytes);
  // Xp: NIMG*XROWS*24 shorts (~19.5 MB) + slack for last-block LDS over-read.

  hipMemsetAsync(Rt, 0, rt_bytes, stream);   // zero pad slots of Rt
  hipLaunchKernelGGL(prep_kernel, dim3(64), dim3(256), 0, stream,
                     P_logit, Q, out, Rt);
  int xthreads = NIMG * XROWS * 12;
  hipLaunchKernelGGL(xconv_kernel, dim3((xthreads + 255) / 256), dim3(256),
                     0, stream, X, (unsigned int*)Xp);
  dim3 grid(2, 8, NIMG);   // u-tiles, l-tiles, images
  hipLaunchKernelGGL(conv_kernel, grid, dim3(256), 0, stream, Xp, Rt, out);
}

// Round 9
// 175.017 us; speedup vs baseline: 1.8350x; 1.8350x over previous
//
#include <hip/hip_runtime.h>
#include <hip/hip_bf16.h>
#include <math.h>

// Problem constants
#define T_ 4
#define N_ 16
#define F_ 6
#define L_ 1024
#define A_ 21
#define K_ 20
#define U_ 256
#define LOUT 1005            // L - K + 1
#define NIMG 384             // T*N*F
#define SZ_S (T_*N_*U_)      // 16384
#define SZ_R (K_*A_*U_)      // 107520

// Packed-X geometry: row stride 24 shorts (48 B). For output row l, contraction
// slot c maps to tap=c/24, col=c%24 (independent of l). Max valid slot =
// 19*24+20 = 476 -> 15 K-steps of 32 (480). Cols 21..23 / tap>=20 zero in R.
#define XPR 24               // shorts per packed row
#define XROWS 1056           // padded rows per image
#define NSTEP 15             // K-steps of 32 slots (480 >= 477)
#define RT_SHORTS (NSTEP * U_ * 32)   // 122880 shorts = 240 KB
#define NBUF 4               // R ring buffers (8 KB each)

typedef __attribute__((ext_vector_type(8))) short short8;   // 8 bf16 (4 VGPR)
typedef __attribute__((ext_vector_type(4))) float f32x4;    // 4 f32 acc

__device__ __forceinline__ unsigned short f2bf(float f) {
  unsigned int u = __float_as_uint(f);
  u += 0x7FFFu + ((u >> 16) & 1u);   // round to nearest even
  return (unsigned short)(u >> 16);
}

__device__ __forceinline__ void atomicMaxF(float* addr, float val) {
  if (val >= 0.f) atomicMax((int*)addr, __float_as_int(val));
  else            atomicMin((unsigned int*)addr, __float_as_uint(val));
}

// Async global->LDS, 16B per lane. LDS dest is wave-uniform base + lane*16.
__device__ __forceinline__ void gload_lds16(const void* g, void* l) {
  __builtin_amdgcn_global_load_lds(
      (const __attribute__((address_space(1))) void*)g,
      (__attribute__((address_space(3))) void*)l, 16, 0, 0);
}

// S init to -inf, R (fp32, exact) into d_out, and Rt = bf16 R scattered into
// slot order: Rt[(s>>5)*(U*32) + u*32 + (s&31)], s = k*24 + a. Pad slots are
// zeroed beforehand by hipMemsetAsync.
__global__ void prep_kernel(const float* __restrict__ P_logit,
                            const float* __restrict__ Q,
                            float* __restrict__ out,
                            unsigned short* __restrict__ Rt) {
  int tid = blockIdx.x * blockDim.x + threadIdx.x;
  if (tid < SZ_S) out[tid] = -INFINITY;
  if (tid >= K_ * U_) return;
  int k = tid / U_;
  int u = tid - k * U_;
  const float* pl = P_logit + (size_t)k * A_ * U_ + u;
  float v[A_];
  float m = -INFINITY;
#pragma unroll
  for (int a = 0; a < A_; ++a) { v[a] = pl[(size_t)a * U_]; m = fmaxf(m, v[a]); }
  float s = 0.f;
#pragma unroll
  for (int a = 0; a < A_; ++a) { v[a] = expf(v[a] - m); s += v[a]; }
  float qs = 0.f;
#pragma unroll
  for (int a = 0; a < A_; ++a) qs += Q[a];
  float eps = qs * (1.0f / A_);
  float invs = 1.f / s;
  float* Rout = out + SZ_S;
#pragma unroll
  for (int a = 0; a < A_; ++a) {
    float r = logf(fmaxf(v[a] * invs / Q[a], eps));
    Rout[(size_t)(k * A_ + a) * U_ + u] = r;
    int sl = k * XPR + a;
    Rt[(size_t)(sl >> 5) * (U_ * 32) + u * 32 + (sl & 31)] = f2bf(r);
  }
}

// X (fp32 [n][1024][21]) -> Xp (bf16 [n][1056][24], zero-padded both dims).
__global__ void xconv_kernel(const float* __restrict__ X,
                             unsigned int* __restrict__ Xp32) {
  int t = blockIdx.x * blockDim.x + threadIdx.x;
  if (t >= NIMG * XROWS * 12) return;
  int w  = t % 12;
  int rl = t / 12;                 // n*XROWS + row
  int row = rl % XROWS;
  int n   = rl / XROWS;
  int c0 = w * 2;
  float v0 = 0.f, v1 = 0.f;
  if (row < L_) {
    const float* xr = X + ((size_t)n * L_ + row) * A_;
    if (c0 < A_)     v0 = xr[c0];
    if (c0 + 1 < A_) v1 = xr[c0 + 1];
  }
  unsigned int o = (unsigned int)f2bf(v0) | ((unsigned int)f2bf(v1) << 16);
  Xp32[(size_t)rl * 12 + w] = o;
}

// Conv as one GEMM: M=u (A=R slots), N=l (B=packed-X window), K=480 (15 steps).
// R de-duplicated through LDS (R8 lesson: per-wave VMEM R reads thrash L1 and
// saturate L2): each 8 KB R-step staged ONCE per block via global_load_lds
// into a 4-slot ring, counted vmcnt(4) (never 0 in steady state), one barrier
// per step (R4-proven scheme). X window (8 KB) staged once.
// Block tile: 128 l x 128 u, 4 waves (2x2), wave 64u x 64l (4x4 frags).
// Both LDS frag patterns are bank-even (8 lanes/bank, no conflict).
__global__ __launch_bounds__(256, 3) void conv_kernel(
    const unsigned short* __restrict__ Xp,
    const unsigned short* __restrict__ Rt,
    float* __restrict__ out) {
  __shared__ __align__(16) unsigned short lds_x[4096];          // 8 KB
  __shared__ __align__(16) unsigned short lds_r[NBUF * 4096];   // 32 KB

  const int n  = blockIdx.z;
  const int l0 = blockIdx.y * 128;
  const int u0 = blockIdx.x * 128;
  const int wid  = threadIdx.x >> 6;
  const int lane = threadIdx.x & 63;

  const char* xsrc = (const char*)Xp + ((size_t)n * XROWS + l0) * (XPR * 2);
  const char* rsrc = (const char*)Rt + (size_t)u0 * 64;   // block's u-half

  // ---- prologue: X (2 chunks/wave) + R steps 0,1,2 (2 chunks/wave each)
#pragma unroll
  for (int r = 0; r < 2; ++r) {
    int c = wid * 2 + r;
    gload_lds16(xsrc + c * 1024 + lane * 16, (char*)lds_x + c * 1024);
  }
#pragma unroll
  for (int kk = 0; kk < 3; ++kk) {
#pragma unroll
    for (int r = 0; r < 2; ++r) {
      int c = wid * 2 + r;
      gload_lds16(rsrc + (size_t)kk * (U_ * 64) + c * 1024 + lane * 16,
                  (char*)lds_r + (kk & (NBUF - 1)) * 8192 + c * 1024);
    }
  }
  // own X + R0 landed (outstanding <= R1,R2 = 4), then certify block-wide
  asm volatile("s_waitcnt vmcnt(4)" ::: "memory");
  __builtin_amdgcn_s_barrier();

  const int wl = wid >> 1;
  const int wu = wid & 1;
  const int fl = lane & 15;            // frag row (A: u) / col (B: l)
  const int fj = lane >> 4;            // k sub-chunk (8 shorts each)

  f32x4 acc[4][4];                     // [ut][lt]
#pragma unroll
  for (int ut = 0; ut < 4; ++ut)
#pragma unroll
    for (int lt = 0; lt < 4; ++lt)
      acc[ut][lt] = (f32x4){0.f, 0.f, 0.f, 0.f};

  // X frag(kk, lt): row (wl*64 + lt*16 + fl), shorts [kk*32 + fj*8 ..)
  const unsigned short* xb = lds_x + (wl * 64 + fl) * XPR + (fj << 3);
  // R frag(kk, ut): ring slot kk&3, u_local = wu*64 + ut*16 + fl
  const int rfo = (wu * 64 + fl) * 32 + (fj << 3);

#pragma unroll 1
  for (int kk = 0; kk < NSTEP; ++kk) {
    short8 xfr[4], rfr[4];
    const unsigned short* rb = lds_r + (kk & (NBUF - 1)) * 4096 + rfo;
#pragma unroll
    for (int lt = 0; lt < 4; ++lt)
      xfr[lt] = *(const short8*)(xb + lt * (16 * XPR) + kk * 32);
#pragma unroll
    for (int ut = 0; ut < 4; ++ut)
      rfr[ut] = *(const short8*)(rb + ut * (16 * 32));

    // stage step kk+3 into ring (slot was read in iter kk-1; barrier-safe)
    if (kk + 3 < NSTEP) {
#pragma unroll
      for (int r = 0; r < 2; ++r) {
        int c = wid * 2 + r;
        gload_lds16(rsrc + (size_t)(kk + 3) * (U_ * 64) + c * 1024 + lane * 16,
                    (char*)lds_r + ((kk + 3) & (NBUF - 1)) * 8192 + c * 1024);
      }
    }

#pragma unroll
    for (int ut = 0; ut < 4; ++ut)
#pragma unroll
      for (int lt = 0; lt < 4; ++lt)
        acc[ut][lt] = __builtin_amdgcn_mfma_f32_16x16x32_bf16(
            rfr[ut], xfr[lt], acc[ut][lt], 0, 0, 0);

    // certify step kk+1 (outstanding {kk+1,kk+2,kk+3} = 6 -> wait to 4)
    if (kk < NSTEP - 3) asm volatile("s_waitcnt vmcnt(4)" ::: "memory");
    else                asm volatile("s_waitcnt vmcnt(0)" ::: "memory");
    __builtin_amdgcn_s_barrier();
  }

  // Epilogue: D layout col(l)=lane&15, row(u)=(lane>>4)*4+reg -> lane holds
  // 4 consecutive u at fixed l => float4 store into row-major Z[l][u].
  float* Z = out + SZ_S + SZ_R;
  const int ug = fj << 2;
  float pmax[4][4];                    // [ut][reg]
#pragma unroll
  for (int ut = 0; ut < 4; ++ut)
#pragma unroll
    for (int r = 0; r < 4; ++r) pmax[ut][r] = -INFINITY;

#pragma unroll
  for (int lt = 0; lt < 4; ++lt) {
    const int l = l0 + wl * 64 + lt * 16 + fl;
    if (l < LOUT) {
      float* zrow = Z + ((size_t)n * LOUT + l) * U_ + u0 + wu * 64 + ug;
#pragma unroll
      for (int ut = 0; ut < 4; ++ut) {
        f32x4 v = acc[ut][lt];
        *(f32x4*)(zrow + ut * 16) = v;
#pragma unroll
        for (int r = 0; r < 4; ++r) pmax[ut][r] = fmaxf(pmax[ut][r], v[r]);
      }
    }
  }

  // Max over the frag's 16 cols (l): xor-reduce over lane&15 (fj preserved).
#pragma unroll
  for (int off = 1; off < 16; off <<= 1)
#pragma unroll
    for (int ut = 0; ut < 4; ++ut)
#pragma unroll
      for (int r = 0; r < 4; ++r)
        pmax[ut][r] = fmaxf(pmax[ut][r], __shfl_xor(pmax[ut][r], off));

  if (fl == 0) {                       // lanes fj*16
    const int tn = n / F_;
    float* Sp = out + (size_t)tn * U_ + u0 + wu * 64 + ug;
#pragma unroll
    for (int ut = 0; ut < 4; ++ut)
#pragma unroll
      for (int r = 0; r < 4; ++r)
        atomicMaxF(Sp + ut * 16 + r, pmax[ut][r]);
  }
}

extern "C" void kernel_launch(void* const* d_in, const int* in_sizes, int n_in,
                              void* d_out, int out_size, void* d_ws, size_t ws_size,
                              hipStream_t stream) {
  const float* X       = (const float*)d_in[0];
  const float* P_logit = (const float*)d_in[1];
  const float* Q       = (const float*)d_in[2];
  float* out = (float*)d_out;

  unsigned short* Rt = (unsigned short*)d_ws;            // 240 KB
  const size_t rt_bytes = (size_t)RT_SHORTS * 2;
  unsigned short* Xp = (unsigned short*)((char*)d_ws + 262144);
  // Xp: NIMG*XROWS*24 shorts (~18.6 MB) + 8 KB slack for last-block LDS
  // stage over-read (staged-but-never-consumed rows).

  hipMemsetAsync(Rt, 0, rt_bytes, stream);   // zero pad slots of Rt
  hipLaunchKernelGGL(prep_kernel, dim3(64), dim3(256), 0, stream,
                     P_logit, Q, out, Rt);
  int xthreads = NIMG * XROWS * 12;
  hipLaunchKernelGGL(xconv_kernel, dim3((xthreads + 255) / 256), dim3(256),
                     0, stream, X, (unsigned int*)Xp);
  dim3 grid(2, 8, NIMG);   // u-tiles, l-tiles, images
  hipLaunchKernelGGL(conv_kernel, grid, dim3(256), 0, stream, Xp, Rt, out);
}

// Round 10
// 162.109 us; speedup vs baseline: 1.9811x; 1.0796x over previous
//
#include <hip/hip_runtime.h>
#include <hip/hip_bf16.h>
#include <math.h>

// Problem constants
#define T_ 4
#define N_ 16
#define F_ 6
#define L_ 1024
#define A_ 21
#define K_ 20
#define U_ 256
#define LOUT 1005            // L - K + 1
#define NIMG 384             // T*N*F
#define SZ_S (T_*N_*U_)      // 16384
#define SZ_R (K_*A_*U_)      // 107520

// Packed-X geometry: row stride 24 shorts (48 B). For output row l, contraction
// slot c maps to tap=c/24, col=c%24 (independent of l). Max valid slot =
// 19*24+20 = 476 -> 15 K-steps of 32 (480). Cols 21..23 / tap>=20 zero in R.
#define XPR 24               // shorts per packed row
#define XROWS 1056           // padded rows per image
#define NSTEP 15             // K-steps of 32 slots (480 >= 477)
#define RT_SHORTS (NSTEP * U_ * 32)   // 122880 shorts = 240 KB
#define NBUF 4               // R ring buffers (8 KB each)
#define XCHUNKS 14           // X LDS chunks of 1 KB (covers 298 rows >= 276)

typedef __attribute__((ext_vector_type(8))) short short8;   // 8 bf16 (4 VGPR)
typedef __attribute__((ext_vector_type(4))) float f32x4;    // 4 f32 acc

__device__ __forceinline__ unsigned short f2bf(float f) {
  unsigned int u = __float_as_uint(f);
  u += 0x7FFFu + ((u >> 16) & 1u);   // round to nearest even
  return (unsigned short)(u >> 16);
}

__device__ __forceinline__ void atomicMaxF(float* addr, float val) {
  if (val >= 0.f) atomicMax((int*)addr, __float_as_int(val));
  else            atomicMin((unsigned int*)addr, __float_as_uint(val));
}

// Async global->LDS, 16B per lane. LDS dest is wave-uniform base + lane*16.
__device__ __forceinline__ void gload_lds16(const void* g, void* l) {
  __builtin_amdgcn_global_load_lds(
      (const __attribute__((address_space(1))) void*)g,
      (__attribute__((address_space(3))) void*)l, 16, 0, 0);
}

// S init to -inf, R (fp32, exact) into d_out, and Rt = bf16 R scattered into
// slot order: Rt[(s>>5)*(U*32) + u*32 + (s&31)], s = k*24 + a. Pad slots are
// zeroed beforehand by hipMemsetAsync.
__global__ void prep_kernel(const float* __restrict__ P_logit,
                            const float* __restrict__ Q,
                            float* __restrict__ out,
                            unsigned short* __restrict__ Rt) {
  int tid = blockIdx.x * blockDim.x + threadIdx.x;
  if (tid < SZ_S) out[tid] = -INFINITY;
  if (tid >= K_ * U_) return;
  int k = tid / U_;
  int u = tid - k * U_;
  const float* pl = P_logit + (size_t)k * A_ * U_ + u;
  float v[A_];
  float m = -INFINITY;
#pragma unroll
  for (int a = 0; a < A_; ++a) { v[a] = pl[(size_t)a * U_]; m = fmaxf(m, v[a]); }
  float s = 0.f;
#pragma unroll
  for (int a = 0; a < A_; ++a) { v[a] = expf(v[a] - m); s += v[a]; }
  float qs = 0.f;
#pragma unroll
  for (int a = 0; a < A_; ++a) qs += Q[a];
  float eps = qs * (1.0f / A_);
  float invs = 1.f / s;
  float* Rout = out + SZ_S;
#pragma unroll
  for (int a = 0; a < A_; ++a) {
    float r = logf(fmaxf(v[a] * invs / Q[a], eps));
    Rout[(size_t)(k * A_ + a) * U_ + u] = r;
    int sl = k * XPR + a;
    Rt[(size_t)(sl >> 5) * (U_ * 32) + u * 32 + (sl & 31)] = f2bf(r);
  }
}

// X (fp32 [n][1024][21]) -> Xp (bf16 [n][1056][24], zero-padded both dims).
__global__ void xconv_kernel(const float* __restrict__ X,
                             unsigned int* __restrict__ Xp32) {
  int t = blockIdx.x * blockDim.x + threadIdx.x;
  if (t >= NIMG * XROWS * 12) return;
  int w  = t % 12;
  int rl = t / 12;                 // n*XROWS + row
  int row = rl % XROWS;
  int n   = rl / XROWS;
  int c0 = w * 2;
  float v0 = 0.f, v1 = 0.f;
  if (row < L_) {
    const float* xr = X + ((size_t)n * L_ + row) * A_;
    if (c0 < A_)     v0 = xr[c0];
    if (c0 + 1 < A_) v1 = xr[c0 + 1];
  }
  unsigned int o = (unsigned int)f2bf(v0) | ((unsigned int)f2bf(v1) << 16);
  Xp32[(size_t)rl * 12 + w] = o;
}

// Conv as one GEMM: M=u (A=R slots), N=l (B=packed-X window), K=480 (15 steps).
// R10 change vs R9: block tile 128u x 256l, wave tile 64u x 128l (4x8 frags,
// 32 MFMA per 12 ds_reads -> reads/MFMA 0.5 -> 0.375, balancing the LDS pipe
// against the matrix pipe at 8 waves/CU), halving block count and R-stage
// traffic. R ring (8 KB/step, 4 slots, counted vmcnt(4), one barrier/step)
// and X one-shot stage are R9's proven scheme.
__global__ __launch_bounds__(256, 2) void conv_kernel(
    const unsigned short* __restrict__ Xp,
    const unsigned short* __restrict__ Rt,
    float* __restrict__ out) {
  __shared__ __align__(16) unsigned short lds_x[XCHUNKS * 512];  // 14 KB
  __shared__ __align__(16) unsigned short lds_r[NBUF * 4096];    // 32 KB

  const int n  = blockIdx.z;
  const int l0 = blockIdx.y * 256;
  const int u0 = blockIdx.x * 128;
  const int wid  = threadIdx.x >> 6;
  const int lane = threadIdx.x & 63;

  const char* xsrc = (const char*)Xp + ((size_t)n * XROWS + l0) * (XPR * 2);
  const char* rsrc = (const char*)Rt + (size_t)u0 * 64;   // block's u-half

  // ---- prologue: X (3-4 chunks/wave) + R steps 0,1,2 (2 chunks/wave each)
  for (int c = wid; c < XCHUNKS; c += 4)
    gload_lds16(xsrc + c * 1024 + lane * 16, (char*)lds_x + c * 1024);
#pragma unroll
  for (int kk = 0; kk < 3; ++kk) {
#pragma unroll
    for (int r = 0; r < 2; ++r) {
      int c = wid * 2 + r;
      gload_lds16(rsrc + (size_t)kk * (U_ * 64) + c * 1024 + lane * 16,
                  (char*)lds_r + (kk & (NBUF - 1)) * 8192 + c * 1024);
    }
  }
  // own X + R0 landed (outstanding <= R1,R2 = 4), then certify block-wide
  asm volatile("s_waitcnt vmcnt(4)" ::: "memory");
  __builtin_amdgcn_s_barrier();

  const int wl = wid >> 1;             // wave l position (0..1), 128 l each
  const int wu = wid & 1;              // wave u position (0..1), 64 u each
  const int fl = lane & 15;            // frag row (A: u) / col (B: l)
  const int fj = lane >> 4;            // k sub-chunk (8 shorts each)

  f32x4 acc[4][8];                     // [ut][lt] = 128 VGPR
#pragma unroll
  for (int ut = 0; ut < 4; ++ut)
#pragma unroll
    for (int lt = 0; lt < 8; ++lt)
      acc[ut][lt] = (f32x4){0.f, 0.f, 0.f, 0.f};

  // X frag(kk, lt): row (wl*128 + lt*16 + fl), byte row*48 + kk*64 + fj*16
  const unsigned short* xb = lds_x + (wl * 128 + fl) * XPR + (fj << 3);
  // R frag(kk, ut): ring slot kk&3, u_local = wu*64 + ut*16 + fl
  const int rfo = (wu * 64 + fl) * 32 + (fj << 3);

#pragma unroll 1
  for (int kk = 0; kk < NSTEP; ++kk) {
    short8 xfr[8], rfr[4];
    const unsigned short* rb = lds_r + (kk & (NBUF - 1)) * 4096 + rfo;
#pragma unroll
    for (int lt = 0; lt < 8; ++lt)
      xfr[lt] = *(const short8*)(xb + lt * (16 * XPR) + kk * 32);
#pragma unroll
    for (int ut = 0; ut < 4; ++ut)
      rfr[ut] = *(const short8*)(rb + ut * (16 * 32));

    // stage step kk+3 into ring (slot was read in iter kk-1; barrier-safe)
    if (kk + 3 < NSTEP) {
#pragma unroll
      for (int r = 0; r < 2; ++r) {
        int c = wid * 2 + r;
        gload_lds16(rsrc + (size_t)(kk + 3) * (U_ * 64) + c * 1024 + lane * 16,
                    (char*)lds_r + ((kk + 3) & (NBUF - 1)) * 8192 + c * 1024);
      }
    }

#pragma unroll
    for (int ut = 0; ut < 4; ++ut)
#pragma unroll
      for (int lt = 0; lt < 8; ++lt)
        acc[ut][lt] = __builtin_amdgcn_mfma_f32_16x16x32_bf16(
            rfr[ut], xfr[lt], acc[ut][lt], 0, 0, 0);

    // certify step kk+1 (outstanding {kk+1,kk+2,kk+3} = 6 -> wait to 4)
    if (kk < NSTEP - 3) asm volatile("s_waitcnt vmcnt(4)" ::: "memory");
    else                asm volatile("s_waitcnt vmcnt(0)" ::: "memory");
    __builtin_amdgcn_s_barrier();
  }

  // Epilogue: D layout col(l)=lane&15, row(u)=(lane>>4)*4+reg -> lane holds
  // 4 consecutive u at fixed l => float4 store into row-major Z[l][u].
  float* Z = out + SZ_S + SZ_R;
  const int ug = fj << 2;
  float pmax[4][4];                    // [ut][reg]
#pragma unroll
  for (int ut = 0; ut < 4; ++ut)
#pragma unroll
    for (int r = 0; r < 4; ++r) pmax[ut][r] = -INFINITY;

#pragma unroll
  for (int lt = 0; lt < 8; ++lt) {
    const int l = l0 + wl * 128 + lt * 16 + fl;
    if (l < LOUT) {
      float* zrow = Z + ((size_t)n * LOUT + l) * U_ + u0 + wu * 64 + ug;
#pragma unroll
      for (int ut = 0; ut < 4; ++ut) {
        f32x4 v = acc[ut][lt];
        *(f32x4*)(zrow + ut * 16) = v;
#pragma unroll
        for (int r = 0; r < 4; ++r) pmax[ut][r] = fmaxf(pmax[ut][r], v[r]);
      }
    }
  }

  // Max over the frag's 16 cols (l): xor-reduce over lane&15 (fj preserved).
#pragma unroll
  for (int off = 1; off < 16; off <<= 1)
#pragma unroll
    for (int ut = 0; ut < 4; ++ut)
#pragma unroll
      for (int r = 0; r < 4; ++r)
        pmax[ut][r] = fmaxf(pmax[ut][r], __shfl_xor(pmax[ut][r], off));

  if (fl == 0) {                       // lanes fj*16
    const int tn = n / F_;
    float* Sp = out + (size_t)tn * U_ + u0 + wu * 64 + ug;
#pragma unroll
    for (int ut = 0; ut < 4; ++ut)
#pragma unroll
      for (int r = 0; r < 4; ++r)
        atomicMaxF(Sp + ut * 16 + r, pmax[ut][r]);
  }
}

extern "C" void kernel_launch(void* const* d_in, const int* in_sizes, int n_in,
                              void* d_out, int out_size, void* d_ws, size_t ws_size,
                              hipStream_t stream) {
  const float* X       = (const float*)d_in[0];
  const float* P_logit = (const float*)d_in[1];
  const float* Q       = (const float*)d_in[2];
  float* out = (float*)d_out;

  unsigned short* Rt = (unsigned short*)d_ws;            // 240 KB
  const size_t rt_bytes = (size_t)RT_SHORTS * 2;
  unsigned short* Xp = (unsigned short*)((char*)d_ws + 262144);
  // Xp: NIMG*XROWS*24 shorts (~18.6 MB) + ~1 KB slack for last-block LDS
  // stage over-read (staged-but-never-consumed rows).

  hipMemsetAsync(Rt, 0, rt_bytes, stream);   // zero pad slots of Rt
  hipLaunchKernelGGL(prep_kernel, dim3(64), dim3(256), 0, stream,
                     P_logit, Q, out, Rt);
  int xthreads = NIMG * XROWS * 12;
  hipLaunchKernelGGL(xconv_kernel, dim3((xthreads + 255) / 256), dim3(256),
                     0, stream, X, (unsigned int*)Xp);
  dim3 grid(2, 4, NIMG);   // u-tiles, l-tiles (256 each), images
  hipLaunchKernelGGL(conv_kernel, grid, dim3(256), 0, stream, Xp, Rt, out);
}

// Round 11
// 156.324 us; speedup vs baseline: 2.0544x; 1.0370x over previous
//
#include <hip/hip_runtime.h>
#include <hip/hip_bf16.h>
#include <math.h>

// Problem constants
#define T_ 4
#define N_ 16
#define F_ 6
#define L_ 1024
#define A_ 21
#define K_ 20
#define U_ 256
#define LOUT 1005            // L - K + 1
#define NIMG 384             // T*N*F
#define SZ_S (T_*N_*U_)      // 16384
#define SZ_R (K_*A_*U_)      // 107520

// Packed-X geometry: row stride 24 shorts (48 B). For output row l, contraction
// slot c maps to tap=c/24, col=c%24 (independent of l). Max valid slot =
// 19*24+20 = 476 -> 15 K-steps of 32 (480). Cols 21..23 / tap>=20 zero in R.
#define XPR 24               // shorts per packed row
#define XROWS 1056           // padded rows per image
#define NSTEP 15             // K-steps of 32 slots (480 >= 477)
#define RT_SHORTS (NSTEP * U_ * 32)   // 122880 shorts = 240 KB
#define NBUF 6               // R ring buffers (8 KB each) -> 48 KB
#define XCHUNKS 14           // X LDS chunks of 1 KB (covers 298 rows >= 276)

typedef __attribute__((ext_vector_type(8))) short short8;   // 8 bf16 (4 VGPR)
typedef __attribute__((ext_vector_type(4))) float f32x4;    // 4 f32 acc

__device__ __forceinline__ unsigned short f2bf(float f) {
  unsigned int u = __float_as_uint(f);
  u += 0x7FFFu + ((u >> 16) & 1u);   // round to nearest even
  return (unsigned short)(u >> 16);
}

__device__ __forceinline__ void atomicMaxF(float* addr, float val) {
  if (val >= 0.f) atomicMax((int*)addr, __float_as_int(val));
  else            atomicMin((unsigned int*)addr, __float_as_uint(val));
}

// Async global->LDS, 16B per lane. LDS dest is wave-uniform base + lane*16.
__device__ __forceinline__ void gload_lds16(const void* g, void* l) {
  __builtin_amdgcn_global_load_lds(
      (const __attribute__((address_space(1))) void*)g,
      (__attribute__((address_space(3))) void*)l, 16, 0, 0);
}

// S init to -inf, R (fp32, exact) into d_out, and Rt = bf16 R scattered into
// slot order: Rt[(s>>5)*(U*32) + u*32 + (s&31)], s = k*24 + a. Pad slots are
// zeroed beforehand by hipMemsetAsync.
__global__ void prep_kernel(const float* __restrict__ P_logit,
                            const float* __restrict__ Q,
                            float* __restrict__ out,
                            unsigned short* __restrict__ Rt) {
  int tid = blockIdx.x * blockDim.x + threadIdx.x;
  if (tid < SZ_S) out[tid] = -INFINITY;
  if (tid >= K_ * U_) return;
  int k = tid / U_;
  int u = tid - k * U_;
  const float* pl = P_logit + (size_t)k * A_ * U_ + u;
  float v[A_];
  float m = -INFINITY;
#pragma unroll
  for (int a = 0; a < A_; ++a) { v[a] = pl[(size_t)a * U_]; m = fmaxf(m, v[a]); }
  float s = 0.f;
#pragma unroll
  for (int a = 0; a < A_; ++a) { v[a] = expf(v[a] - m); s += v[a]; }
  float qs = 0.f;
#pragma unroll
  for (int a = 0; a < A_; ++a) qs += Q[a];
  float eps = qs * (1.0f / A_);
  float invs = 1.f / s;
  float* Rout = out + SZ_S;
#pragma unroll
  for (int a = 0; a < A_; ++a) {
    float r = logf(fmaxf(v[a] * invs / Q[a], eps));
    Rout[(size_t)(k * A_ + a) * U_ + u] = r;
    int sl = k * XPR + a;
    Rt[(size_t)(sl >> 5) * (U_ * 32) + u * 32 + (sl & 31)] = f2bf(r);
  }
}

// X (fp32 [n][1024][21]) -> Xp (bf16 [n][1056][24], zero-padded both dims).
__global__ void xconv_kernel(const float* __restrict__ X,
                             unsigned int* __restrict__ Xp32) {
  int t = blockIdx.x * blockDim.x + threadIdx.x;
  if (t >= NIMG * XROWS * 12) return;
  int w  = t % 12;
  int rl = t / 12;                 // n*XROWS + row
  int row = rl % XROWS;
  int n   = rl / XROWS;
  int c0 = w * 2;
  float v0 = 0.f, v1 = 0.f;
  if (row < L_) {
    const float* xr = X + ((size_t)n * L_ + row) * A_;
    if (c0 < A_)     v0 = xr[c0];
    if (c0 + 1 < A_) v1 = xr[c0 + 1];
  }
  unsigned int o = (unsigned int)f2bf(v0) | ((unsigned int)f2bf(v1) << 16);
  Xp32[(size_t)rl * 12 + w] = o;
}

// Conv as one GEMM: M=u (A=R slots), N=l (B=packed-X window), K=480 (15 steps).
// R11 change vs R10: PAIR iterations -- 2 K-steps per barrier/vmcnt (8
// barriers not 15), NBUF=6 ring (read {2p,2p+1}, future {2p+2,2p+3}, stage
// {2p+4,2p+5}: distinct mod 6), stage issued at iteration TOP (latency hides
// under 64 MFMA), s_setprio(1) around MFMA clusters (T5). Both pair-slots are
// certified at iteration entry so step 2p+1's ds_reads hoist under step 2p's
// MFMAs. Block 128u x 256l, wave 64u x 128l (4x8 frags).
__global__ __launch_bounds__(256, 2) void conv_kernel(
    const unsigned short* __restrict__ Xp,
    const unsigned short* __restrict__ Rt,
    float* __restrict__ out) {
  __shared__ __align__(16) unsigned short lds_x[XCHUNKS * 512];  // 14 KB
  __shared__ __align__(16) unsigned short lds_r[NBUF * 4096];    // 48 KB

  const int n  = blockIdx.z;
  const int l0 = blockIdx.y * 256;
  const int u0 = blockIdx.x * 128;
  const int wid  = threadIdx.x >> 6;
  const int lane = threadIdx.x & 63;

  const char* xsrc = (const char*)Xp + ((size_t)n * XROWS + l0) * (XPR * 2);
  const char* rsrc = (const char*)Rt + (size_t)u0 * 64;   // block's u-half

  // ---- prologue: X (3-4 chunks/wave) + R steps 0..3 (2 chunks/wave each)
  for (int c = wid; c < XCHUNKS; c += 4)
    gload_lds16(xsrc + c * 1024 + lane * 16, (char*)lds_x + c * 1024);
#pragma unroll
  for (int kk = 0; kk < 4; ++kk) {
#pragma unroll
    for (int r = 0; r < 2; ++r) {
      int c = wid * 2 + r;
      gload_lds16(rsrc + (size_t)kk * (U_ * 64) + c * 1024 + lane * 16,
                  (char*)lds_r + (kk % NBUF) * 8192 + c * 1024);
    }
  }
  // need X + steps 0,1 done; steps 2,3 (4 loads) may stay in flight
  asm volatile("s_waitcnt vmcnt(4)" ::: "memory");
  __builtin_amdgcn_s_barrier();

  const int wl = wid >> 1;             // wave l position (0..1), 128 l each
  const int wu = wid & 1;              // wave u position (0..1), 64 u each
  const int fl = lane & 15;            // frag row (A: u) / col (B: l)
  const int fj = lane >> 4;            // k sub-chunk (8 shorts each)

  f32x4 acc[4][8];                     // [ut][lt] = 128 VGPR
#pragma unroll
  for (int ut = 0; ut < 4; ++ut)
#pragma unroll
    for (int lt = 0; lt < 8; ++lt)
      acc[ut][lt] = (f32x4){0.f, 0.f, 0.f, 0.f};

  // X frag(kk, lt): row (wl*128 + lt*16 + fl), shorts kk*32 + fj*8
  const unsigned short* xb = lds_x + (wl * 128 + fl) * XPR + (fj << 3);
  // R frag(kk, ut): ring slot kk%6, u_local = wu*64 + ut*16 + fl
  const int rfo = (wu * 64 + fl) * 32 + (fj << 3);

#define STEP_BODY(KK, SLOT)                                                  \
  {                                                                          \
    short8 xfr[8], rfr[4];                                                   \
    const unsigned short* rb = lds_r + (SLOT) * 4096 + rfo;                  \
    _Pragma("unroll")                                                        \
    for (int lt = 0; lt < 8; ++lt)                                           \
      xfr[lt] = *(const short8*)(xb + lt * (16 * XPR) + (KK) * 32);          \
    _Pragma("unroll")                                                        \
    for (int ut = 0; ut < 4; ++ut)                                           \
      rfr[ut] = *(const short8*)(rb + ut * (16 * 32));                       \
    __builtin_amdgcn_s_setprio(1);                                           \
    _Pragma("unroll")                                                        \
    for (int ut = 0; ut < 4; ++ut)                                           \
      _Pragma("unroll")                                                      \
      for (int lt = 0; lt < 8; ++lt)                                         \
        acc[ut][lt] = __builtin_amdgcn_mfma_f32_16x16x32_bf16(               \
            rfr[ut], xfr[lt], acc[ut][lt], 0, 0, 0);                         \
    __builtin_amdgcn_s_setprio(0);                                           \
  }

#define STAGE_STEP(KK)                                                       \
  {                                                                          \
    _Pragma("unroll")                                                        \
    for (int r = 0; r < 2; ++r) {                                            \
      int c = wid * 2 + r;                                                   \
      gload_lds16(rsrc + (size_t)(KK) * (U_ * 64) + c * 1024 + lane * 16,    \
                  (char*)lds_r + ((KK) % NBUF) * 8192 + c * 1024);           \
    }                                                                        \
  }

#pragma unroll
  for (int p = 0; p < 7; ++p) {
    const int k0 = 2 * p;
    // stage pair {k0+4, k0+5} first (latency hides under this pair's MFMAs)
    if (k0 + 4 < NSTEP) STAGE_STEP(k0 + 4);
    if (k0 + 5 < NSTEP) STAGE_STEP(k0 + 5);
    STEP_BODY(k0,     (k0) % NBUF);
    STEP_BODY(k0 + 1, (k0 + 1) % NBUF);
    // certify pair {k0+2, k0+3}: leave only {k0+4, k0+5} in flight
    if (k0 + 5 < NSTEP)      asm volatile("s_waitcnt vmcnt(4)" ::: "memory");
    else if (k0 + 4 < NSTEP) asm volatile("s_waitcnt vmcnt(2)" ::: "memory");
    else                     asm volatile("s_waitcnt vmcnt(0)" ::: "memory");
    __builtin_amdgcn_s_barrier();
  }
  // tail: step 14 (slot 2), certified by the last vmcnt(0)+barrier
  STEP_BODY(14, 14 % NBUF);

#undef STEP_BODY
#undef STAGE_STEP

  // Epilogue: D layout col(l)=lane&15, row(u)=(lane>>4)*4+reg -> lane holds
  // 4 consecutive u at fixed l => float4 store into row-major Z[l][u].
  float* Z = out + SZ_S + SZ_R;
  const int ug = fj << 2;
  float pmax[4][4];                    // [ut][reg]
#pragma unroll
  for (int ut = 0; ut < 4; ++ut)
#pragma unroll
    for (int r = 0; r < 4; ++r) pmax[ut][r] = -INFINITY;

#pragma unroll
  for (int lt = 0; lt < 8; ++lt) {
    const int l = l0 + wl * 128 + lt * 16 + fl;
    if (l < LOUT) {
      float* zrow = Z + ((size_t)n * LOUT + l) * U_ + u0 + wu * 64 + ug;
#pragma unroll
      for (int ut = 0; ut < 4; ++ut) {
        f32x4 v = acc[ut][lt];
        *(f32x4*)(zrow + ut * 16) = v;
#pragma unroll
        for (int r = 0; r < 4; ++r) pmax[ut][r] = fmaxf(pmax[ut][r], v[r]);
      }
    }
  }

  // Max over the frag's 16 cols (l): xor-reduce over lane&15 (fj preserved).
#pragma unroll
  for (int off = 1; off < 16; off <<= 1)
#pragma unroll
    for (int ut = 0; ut < 4; ++ut)
#pragma unroll
      for (int r = 0; r < 4; ++r)
        pmax[ut][r] = fmaxf(pmax[ut][r], __shfl_xor(pmax[ut][r], off));

  if (fl == 0) {                       // lanes fj*16
    const int tn = n / F_;
    float* Sp = out + (size_t)tn * U_ + u0 + wu * 64 + ug;
#pragma unroll
    for (int ut = 0; ut < 4; ++ut)
#pragma unroll
      for (int r = 0; r < 4; ++r)
        atomicMaxF(Sp + ut * 16 + r, pmax[ut][r]);
  }
}

extern "C" void kernel_launch(void* const* d_in, const int* in_sizes, int n_in,
                              void* d_out, int out_size, void* d_ws, size_t ws_size,
                              hipStream_t stream) {
  const float* X       = (const float*)d_in[0];
  const float* P_logit = (const float*)d_in[1];
  const float* Q       = (const float*)d_in[2];
  float* out = (float*)d_out;

  unsigned short* Rt = (unsigned short*)d_ws;            // 240 KB
  const size_t rt_bytes = (size_t)RT_SHORTS * 2;
  unsigned short* Xp = (unsigned short*)((char*)d_ws + 262144);
  // Xp: NIMG*XROWS*24 shorts (~18.6 MB); block LDS over-read stays inside Xp.

  hipMemsetAsync(Rt, 0, rt_bytes, stream);   // zero pad slots of Rt
  hipLaunchKernelGGL(prep_kernel, dim3(64), dim3(256), 0, stream,
                     P_logit, Q, out, Rt);
  int xthreads = NIMG * XROWS * 12;
  hipLaunchKernelGGL(xconv_kernel, dim3((xthreads + 255) / 256), dim3(256),
                     0, stream, X, (unsigned int*)Xp);
  dim3 grid(2, 4, NIMG);   // u-tiles, l-tiles (256 each), images
  hipLaunchKernelGGL(conv_kernel, grid, dim3(256), 0, stream, Xp, Rt, out);
}

// Round 12
// 151.590 us; speedup vs baseline: 2.1186x; 1.0312x over previous
//
#include <hip/hip_runtime.h>
#include <hip/hip_bf16.h>
#include <math.h>

// Problem constants
#define T_ 4
#define N_ 16
#define F_ 6
#define L_ 1024
#define A_ 21
#define K_ 20
#define U_ 256
#define LOUT 1005            // L - K + 1
#define NIMG 384             // T*N*F
#define SZ_S (T_*N_*U_)      // 16384
#define SZ_R (K_*A_*U_)      // 107520

// Packed-X geometry: row stride 24 shorts (48 B). For output row l, contraction
// slot c maps to tap=c/24, col=c%24 (independent of l). Valid slots 0..476;
// steps padded to 16 (512 slots), step 15 + cols 21..23 + tap>=20 zero in R.
#define XPR 24               // shorts per packed row
#define XROWS 1056           // padded rows per image
#define NSTEP 16             // K-steps of 32 slots (padded; step 15 = zeros)
#define RT_SHORTS (NSTEP * U_ * 32)   // 131072 shorts = 256 KB
#define NBUF 8               // R ring buffers (8 KB each) -> 64 KB
#define XCHUNKS 14           // X LDS chunks of 1 KB (covers 298 rows >= 276)

typedef __attribute__((ext_vector_type(8))) short short8;   // 8 bf16 (4 VGPR)
typedef __attribute__((ext_vector_type(4))) float f32x4;    // 4 f32 acc

__device__ __forceinline__ unsigned short f2bf(float f) {
  unsigned int u = __float_as_uint(f);
  u += 0x7FFFu + ((u >> 16) & 1u);   // round to nearest even
  return (unsigned short)(u >> 16);
}

__device__ __forceinline__ void atomicMaxF(float* addr, float val) {
  if (val >= 0.f) atomicMax((int*)addr, __float_as_int(val));
  else            atomicMin((unsigned int*)addr, __float_as_uint(val));
}

// Async global->LDS, 16B per lane. LDS dest is wave-uniform base + lane*16.
__device__ __forceinline__ void gload_lds16(const void* g, void* l) {
  __builtin_amdgcn_global_load_lds(
      (const __attribute__((address_space(1))) void*)g,
      (__attribute__((address_space(3))) void*)l, 16, 0, 0);
}

// S init to -inf; R (fp32, exact) into d_out; Rt = bf16 R scattered into slot
// order Rt[(s>>5)*(U*32) + u*32 + (s&31)], s = k*24 + a, with ALL pad slots
// zeroed here (cols 21..23 per tap; whole step 15) -- no memset needed.
__global__ void prep_kernel(const float* __restrict__ P_logit,
                            const float* __restrict__ Q,
                            float* __restrict__ out,
                            unsigned short* __restrict__ Rt) {
  int tid = blockIdx.x * blockDim.x + threadIdx.x;
  if (tid < SZ_S) out[tid] = -INFINITY;
  if (tid < U_ * 32) Rt[15 * (U_ * 32) + tid] = 0;   // zero padded step 15
  if (tid >= K_ * U_) return;
  int k = tid / U_;
  int u = tid - k * U_;
  const float* pl = P_logit + (size_t)k * A_ * U_ + u;
  float v[A_];
  float m = -INFINITY;
#pragma unroll
  for (int a = 0; a < A_; ++a) { v[a] = pl[(size_t)a * U_]; m = fmaxf(m, v[a]); }
  float s = 0.f;
#pragma unroll
  for (int a = 0; a < A_; ++a) { v[a] = expf(v[a] - m); s += v[a]; }
  float qs = 0.f;
#pragma unroll
  for (int a = 0; a < A_; ++a) qs += Q[a];
  float eps = qs * (1.0f / A_);
  float invs = 1.f / s;
  float* Rout = out + SZ_S;
#pragma unroll
  for (int a = 0; a < A_; ++a) {
    float r = logf(fmaxf(v[a] * invs / Q[a], eps));
    Rout[(size_t)(k * A_ + a) * U_ + u] = r;
    int sl = k * XPR + a;
    Rt[(size_t)(sl >> 5) * (U_ * 32) + u * 32 + (sl & 31)] = f2bf(r);
  }
#pragma unroll
  for (int a = A_; a < XPR; ++a) {                   // zero pad cols 21..23
    int sl = k * XPR + a;
    Rt[(size_t)(sl >> 5) * (U_ * 32) + u * 32 + (sl & 31)] = 0;
  }
}

// X (fp32 [n][1024][21]) -> Xp (bf16 [n][1056][24], zero-padded both dims).
__global__ void xconv_kernel(const float* __restrict__ X,
                             unsigned int* __restrict__ Xp32) {
  int t = blockIdx.x * blockDim.x + threadIdx.x;
  if (t >= NIMG * XROWS * 12) return;
  int w  = t % 12;
  int rl = t / 12;                 // n*XROWS + row
  int row = rl % XROWS;
  int n   = rl / XROWS;
  int c0 = w * 2;
  float v0 = 0.f, v1 = 0.f;
  if (row < L_) {
    const float* xr = X + ((size_t)n * L_ + row) * A_;
    if (c0 < A_)     v0 = xr[c0];
    if (c0 + 1 < A_) v1 = xr[c0 + 1];
  }
  unsigned int o = (unsigned int)f2bf(v0) | ((unsigned int)f2bf(v1) << 16);
  Xp32[(size_t)rl * 12 + w] = o;
}

// Conv as one GEMM: M=u (A=R slots), N=l (B=packed-X window), K=512 (16 steps,
// step 15 zero-padded). R12 change vs R11: NBUF=8 deep ring + REGISTER-CARRIED
// fragments across the barrier -- pair p+1's LDS slots are certified one full
// iteration early (vmcnt(4) leaves only pair p+3 in flight), so step 2p+2's
// frags are pre-read into regs DURING iter p, under the MFMA clusters; each
// iter starts MFMAs immediately at barrier exit. 8 uniform pair-iterations,
// stage pair p+3 at top (p<=4). Block 128u x 256l, wave 64u x 128l.
__global__ __launch_bounds__(256, 2) void conv_kernel(
    const unsigned short* __restrict__ Xp,
    const unsigned short* __restrict__ Rt,
    float* __restrict__ out) {
  __shared__ __align__(16) unsigned short lds_x[XCHUNKS * 512];  // 14 KB
  __shared__ __align__(16) unsigned short lds_r[NBUF * 4096];    // 64 KB

  const int n  = blockIdx.z;
  const int l0 = blockIdx.y * 256;
  const int u0 = blockIdx.x * 128;
  const int wid  = threadIdx.x >> 6;
  const int lane = threadIdx.x & 63;

  const char* xsrc = (const char*)Xp + ((size_t)n * XROWS + l0) * (XPR * 2);
  const char* rsrc = (const char*)Rt + (size_t)u0 * 64;   // block's u-half

#define STAGE_STEP(KK)                                                       \
  {                                                                          \
    _Pragma("unroll")                                                        \
    for (int r = 0; r < 2; ++r) {                                            \
      int c = wid * 2 + r;                                                   \
      gload_lds16(rsrc + (size_t)(KK) * (U_ * 64) + c * 1024 + lane * 16,    \
                  (char*)lds_r + ((KK) & (NBUF - 1)) * 8192 + c * 1024);     \
    }                                                                        \
  }

  // ---- prologue: X (3-4 chunks/wave) + steps 0..5 (pairs 0..2)
  for (int c = wid; c < XCHUNKS; c += 4)
    gload_lds16(xsrc + c * 1024 + lane * 16, (char*)lds_x + c * 1024);
#pragma unroll
  for (int kk = 0; kk < 6; ++kk) STAGE_STEP(kk);
  // certify X + pair 0,1 (steps 0..3); leave pair 2 (4 loads) in flight
  asm volatile("s_waitcnt vmcnt(4)" ::: "memory");
  __builtin_amdgcn_s_barrier();

  const int wl = wid >> 1;             // wave l position (0..1), 128 l each
  const int wu = wid & 1;              // wave u position (0..1), 64 u each
  const int fl = lane & 15;            // frag row (A: u) / col (B: l)
  const int fj = lane >> 4;            // k sub-chunk (8 shorts each)

  f32x4 acc[4][8];                     // [ut][lt] = 128 VGPR
#pragma unroll
  for (int ut = 0; ut < 4; ++ut)
#pragma unroll
    for (int lt = 0; lt < 8; ++lt)
      acc[ut][lt] = (f32x4){0.f, 0.f, 0.f, 0.f};

  // X frag(kk, lt): row (wl*128 + lt*16 + fl), shorts kk*32 + fj*8
  const unsigned short* xb = lds_x + (wl * 128 + fl) * XPR + (fj << 3);
  // R frag(kk, ut): ring slot kk&7, u_local = wu*64 + ut*16 + fl
  const int rfo = (wu * 64 + fl) * 32 + (fj << 3);

#define READ_FRAGS(KK, X8, R4)                                               \
  {                                                                          \
    const unsigned short* rb = lds_r + ((KK) & (NBUF - 1)) * 4096 + rfo;     \
    _Pragma("unroll")                                                        \
    for (int lt = 0; lt < 8; ++lt)                                           \
      (X8)[lt] = *(const short8*)(xb + lt * (16 * XPR) + (KK) * 32);         \
    _Pragma("unroll")                                                        \
    for (int ut = 0; ut < 4; ++ut)                                           \
      (R4)[ut] = *(const short8*)(rb + ut * (16 * 32));                      \
  }

#define MFMA32(R4, X8)                                                       \
  {                                                                          \
    __builtin_amdgcn_s_setprio(1);                                           \
    _Pragma("unroll")                                                        \
    for (int ut = 0; ut < 4; ++ut)                                           \
      _Pragma("unroll")                                                      \
      for (int lt = 0; lt < 8; ++lt)                                         \
        acc[ut][lt] = __builtin_amdgcn_mfma_f32_16x16x32_bf16(               \
            (R4)[ut], (X8)[lt], acc[ut][lt], 0, 0, 0);                       \
    __builtin_amdgcn_s_setprio(0);                                           \
  }

  short8 fx[2][8], fr[2][4];           // ping-pong carried fragments
  READ_FRAGS(0, fx[0], fr[0]);         // pair 0 certified above

#pragma unroll
  for (int p = 0; p < 8; ++p) {
    const int cb = p & 1, nb = cb ^ 1;
    // stage pair p+3 (steps 2p+6, 2p+7) -- hides under this iter's MFMAs
    if (p <= 4) { STAGE_STEP(2 * p + 6); STAGE_STEP(2 * p + 7); }
    // step 2p: fragments already in registers -> MFMA at barrier exit
    MFMA32(fr[cb], fx[cb]);
    // step 2p+1 (slot certified since end of iter p-2)
    short8 xt[8], rt4[4];
    READ_FRAGS(2 * p + 1, xt, rt4);
    MFMA32(rt4, xt);
    // carry step 2p+2 (slot certified end of iter p-1)
    if (p < 7) READ_FRAGS(2 * p + 2, fx[nb], fr[nb]);
    // certify pair p+2; leave only pair p+3 in flight
    if (p <= 4) asm volatile("s_waitcnt vmcnt(4)" ::: "memory");
    else        asm volatile("s_waitcnt vmcnt(0)" ::: "memory");
    __builtin_amdgcn_s_barrier();
  }

#undef READ_FRAGS
#undef MFMA32
#undef STAGE_STEP

  // Epilogue: D layout col(l)=lane&15, row(u)=(lane>>4)*4+reg -> lane holds
  // 4 consecutive u at fixed l => float4 store into row-major Z[l][u].
  float* Z = out + SZ_S + SZ_R;
  const int ug = fj << 2;
  float pmax[4][4];                    // [ut][reg]
#pragma unroll
  for (int ut = 0; ut < 4; ++ut)
#pragma unroll
    for (int r = 0; r < 4; ++r) pmax[ut][r] = -INFINITY;

#pragma unroll
  for (int lt = 0; lt < 8; ++lt) {
    const int l = l0 + wl * 128 + lt * 16 + fl;
    if (l < LOUT) {
      float* zrow = Z + ((size_t)n * LOUT + l) * U_ + u0 + wu * 64 + ug;
#pragma unroll
      for (int ut = 0; ut < 4; ++ut) {
        f32x4 v = acc[ut][lt];
        *(f32x4*)(zrow + ut * 16) = v;
#pragma unroll
        for (int r = 0; r < 4; ++r) pmax[ut][r] = fmaxf(pmax[ut][r], v[r]);
      }
    }
  }

  // Max over the frag's 16 cols (l): xor-reduce over lane&15 (fj preserved).
#pragma unroll
  for (int off = 1; off < 16; off <<= 1)
#pragma unroll
    for (int ut = 0; ut < 4; ++ut)
#pragma unroll
      for (int r = 0; r < 4; ++r)
        pmax[ut][r] = fmaxf(pmax[ut][r], __shfl_xor(pmax[ut][r], off));

  if (fl == 0) {                       // lanes fj*16
    const int tn = n / F_;
    float* Sp = out + (size_t)tn * U_ + u0 + wu * 64 + ug;
#pragma unroll
    for (int ut = 0; ut < 4; ++ut)
#pragma unroll
      for (int r = 0; r < 4; ++r)
        atomicMaxF(Sp + ut * 16 + r, pmax[ut][r]);
  }
}

extern "C" void kernel_launch(void* const* d_in, const int* in_sizes, int n_in,
                              void* d_out, int out_size, void* d_ws, size_t ws_size,
                              hipStream_t stream) {
  const float* X       = (const float*)d_in[0];
  const float* P_logit = (const float*)d_in[1];
  const float* Q       = (const float*)d_in[2];
  float* out = (float*)d_out;

  unsigned short* Rt = (unsigned short*)d_ws;            // 256 KB
  unsigned short* Xp = (unsigned short*)((char*)d_ws + 262144);
  // Xp: NIMG*XROWS*24 shorts (~18.6 MB) + ~1 KB slack for last-block LDS
  // stage over-read (staged-but-never-consumed rows).

  hipLaunchKernelGGL(prep_kernel, dim3(64), dim3(256), 0, stream,
                     P_logit, Q, out, Rt);
  int xthreads = NIMG * XROWS * 12;
  hipLaunchKernelGGL(xconv_kernel, dim3((xthreads + 255) / 256), dim3(256),
                     0, stream, X, (unsigned int*)Xp);
  dim3 grid(2, 4, NIMG);   // u-tiles, l-tiles (256 each), images
  hipLaunchKernelGGL(conv_kernel, grid, dim3(256), 0, stream, Xp, Rt, out);
}

// Round 13
// 148.394 us; speedup vs baseline: 2.1642x; 1.0215x over previous
//
#include <hip/hip_runtime.h>
#include <hip/hip_bf16.h>
#include <math.h>

// Problem constants
#define T_ 4
#define N_ 16
#define F_ 6
#define L_ 1024
#define A_ 21
#define K_ 20
#define U_ 256
#define LOUT 1005            // L - K + 1
#define NIMG 384             // T*N*F
#define SZ_S (T_*N_*U_)      // 16384
#define SZ_R (K_*A_*U_)      // 107520

// Packed-X geometry: row stride 24 shorts (48 B). For output row l, contraction
// slot c maps to tap=c/24, col=c%24 (independent of l). Valid slots 0..476 ->
// 15 K-steps of 32 (480); cols 21..23 (incl. slots 477..479) zero in R.
#define XPR 24               // shorts per packed row
#define XROWS 1056           // padded rows per image
#define NSTEP 15             // K-steps of 32 slots
#define RT_SHORTS (NSTEP * U_ * 32)   // 122880 shorts = 240 KB
#define XCHUNKS 14           // X LDS chunks of 1 KB (covers 298 rows >= 277)

typedef __attribute__((ext_vector_type(8))) short short8;   // 8 bf16 (4 VGPR)
typedef __attribute__((ext_vector_type(4))) float f32x4;    // 4 f32 acc

__device__ __forceinline__ unsigned short f2bf(float f) {
  unsigned int u = __float_as_uint(f);
  u += 0x7FFFu + ((u >> 16) & 1u);   // round to nearest even
  return (unsigned short)(u >> 16);
}

__device__ __forceinline__ void atomicMaxF(float* addr, float val) {
  if (val >= 0.f) atomicMax((int*)addr, __float_as_int(val));
  else            atomicMin((unsigned int*)addr, __float_as_uint(val));
}

// Async global->LDS, 16B per lane. LDS dest is wave-uniform base + lane*16.
__device__ __forceinline__ void gload_lds16(const void* g, void* l) {
  __builtin_amdgcn_global_load_lds(
      (const __attribute__((address_space(1))) void*)g,
      (__attribute__((address_space(3))) void*)l, 16, 0, 0);
}

// S init to -inf; R (fp32, exact) into d_out; Rt = bf16 R scattered into slot
// order Rt[(s>>5)*(U*32) + u*32 + (s&31)], s = k*24 + a; pad cols 21..23 (which
// include slots 477..479) zeroed here -- no memset pass needed.
__global__ void prep_kernel(const float* __restrict__ P_logit,
                            const float* __restrict__ Q,
                            float* __restrict__ out,
                            unsigned short* __restrict__ Rt) {
  int tid = blockIdx.x * blockDim.x + threadIdx.x;
  if (tid < SZ_S) out[tid] = -INFINITY;
  if (tid >= K_ * U_) return;
  int k = tid / U_;
  int u = tid - k * U_;
  const float* pl = P_logit + (size_t)k * A_ * U_ + u;
  float v[A_];
  float m = -INFINITY;
#pragma unroll
  for (int a = 0; a < A_; ++a) { v[a] = pl[(size_t)a * U_]; m = fmaxf(m, v[a]); }
  float s = 0.f;
#pragma unroll
  for (int a = 0; a < A_; ++a) { v[a] = expf(v[a] - m); s += v[a]; }
  float qs = 0.f;
#pragma unroll
  for (int a = 0; a < A_; ++a) qs += Q[a];
  float eps = qs * (1.0f / A_);
  float invs = 1.f / s;
  float* Rout = out + SZ_S;
#pragma unroll
  for (int a = 0; a < A_; ++a) {
    float r = logf(fmaxf(v[a] * invs / Q[a], eps));
    Rout[(size_t)(k * A_ + a) * U_ + u] = r;
    int sl = k * XPR + a;
    Rt[(size_t)(sl >> 5) * (U_ * 32) + u * 32 + (sl & 31)] = f2bf(r);
  }
#pragma unroll
  for (int a = A_; a < XPR; ++a) {                   // zero pad cols 21..23
    int sl = k * XPR + a;
    Rt[(size_t)(sl >> 5) * (U_ * 32) + u * 32 + (sl & 31)] = 0;
  }
}

// X (fp32 [n][1024][21]) -> Xp (bf16 [n][1056][24], zero-padded both dims).
__global__ void xconv_kernel(const float* __restrict__ X,
                             unsigned int* __restrict__ Xp32) {
  int t = blockIdx.x * blockDim.x + threadIdx.x;
  if (t >= NIMG * XROWS * 12) return;
  int w  = t % 12;
  int rl = t / 12;                 // n*XROWS + row
  int row = rl % XROWS;
  int n   = rl / XROWS;
  int c0 = w * 2;
  float v0 = 0.f, v1 = 0.f;
  if (row < L_) {
    const float* xr = X + ((size_t)n * L_ + row) * A_;
    if (c0 < A_)     v0 = xr[c0];
    if (c0 + 1 < A_) v1 = xr[c0 + 1];
  }
  unsigned int o = (unsigned int)f2bf(v0) | ((unsigned int)f2bf(v1) << 16);
  Xp32[(size_t)rl * 12 + w] = o;
}

// Conv as one GEMM: M=u (A=R slots), N=l (B=packed-X window), K=480 (15 steps).
// R13 change vs R12: BARRIER-FREE K-loop. Each wave owns a PRIVATE 16 KB R
// ring (4 slots x 4 KB = its wu-half of a step), stages it itself via
// global_load_lds and certifies with its own per-wave vmcnt -- no s_barrier
// after the prologue, so waves free-run and stagger (smoothing LDS pipe and
// store drain). X staged once, shared, certified by the single prologue
// barrier. Register-carried frags (read k+1 under MFMA k, static ping-pong).
// Steady-state vmcnt(8) certifies step k+1 (slots k+2,k+3 in flight).
// Block 128u x 256l, wave 64u x 128l (4x8 16x16 frags).
__global__ __launch_bounds__(256, 2) void conv_kernel(
    const unsigned short* __restrict__ Xp,
    const unsigned short* __restrict__ Rt,
    float* __restrict__ out) {
  __shared__ __align__(16) unsigned short lds_x[XCHUNKS * 512];   // 14 KB
  __shared__ __align__(16) unsigned short lds_r[4][4][2048];      // 64 KB

  const int n  = blockIdx.z;
  const int l0 = blockIdx.y * 256;
  const int u0 = blockIdx.x * 128;
  const int wid  = threadIdx.x >> 6;
  const int lane = threadIdx.x & 63;
  const int wl = wid >> 1;             // wave l position (0..1), 128 l each
  const int wu = wid & 1;              // wave u position (0..1), 64 u each

  const char* xsrc = (const char*)Xp + ((size_t)n * XROWS + l0) * (XPR * 2);
  // wave's private R source: its wu-half (4 KB) of each 16 KB step
  const char* rsrc = (const char*)Rt + (size_t)u0 * 64 + wu * 4096;
  char* rdst = (char*)&lds_r[wid][0][0];

#define STAGE(KK)                                                            \
  {                                                                          \
    _Pragma("unroll")                                                        \
    for (int c = 0; c < 4; ++c)                                              \
      gload_lds16(rsrc + (size_t)(KK) * (U_ * 64) + c * 1024 + lane * 16,    \
                  rdst + ((KK) & 3) * 4096 + c * 1024);                      \
  }

  // ---- prologue: X (3-4 chunks/wave, shared) + private R steps 0..2
  for (int c = wid; c < XCHUNKS; c += 4)
    gload_lds16(xsrc + c * 1024 + lane * 16, (char*)lds_x + c * 1024);
  STAGE(0) STAGE(1) STAGE(2)
  // X loads are oldest; 12 R loads may remain in flight
  asm volatile("s_waitcnt vmcnt(12)" ::: "memory");
  __builtin_amdgcn_s_barrier();        // the ONLY barrier: X visible to all

  const int fl = lane & 15;            // frag row (A: u) / col (B: l)
  const int fj = lane >> 4;            // k sub-chunk (8 shorts each)

  f32x4 acc[4][8];                     // [ut][lt] = 128 VGPR
#pragma unroll
  for (int ut = 0; ut < 4; ++ut)
#pragma unroll
    for (int lt = 0; lt < 8; ++lt)
      acc[ut][lt] = (f32x4){0.f, 0.f, 0.f, 0.f};

  // X frag(kk, lt): row (wl*128 + lt*16 + fl), shorts kk*32 + fj*8
  const unsigned short* xb = lds_x + (wl * 128 + fl) * XPR + (fj << 3);
  // R frag(kk, ut): private slot kk&3, row (ut*16 + fl) of the 64-row half
  const unsigned short* rbw =
      (const unsigned short*)rdst + fl * 32 + (fj << 3);

#define READ_FRAGS(KK, X8, R4)                                               \
  {                                                                          \
    const unsigned short* rb = rbw + ((KK) & 3) * 2048;                      \
    _Pragma("unroll")                                                        \
    for (int lt = 0; lt < 8; ++lt)                                           \
      (X8)[lt] = *(const short8*)(xb + lt * (16 * XPR) + (KK) * 32);         \
    _Pragma("unroll")                                                        \
    for (int ut = 0; ut < 4; ++ut)                                           \
      (R4)[ut] = *(const short8*)(rb + ut * (16 * 32));                      \
  }

#define MFMA32(R4, X8)                                                       \
  {                                                                          \
    __builtin_amdgcn_s_setprio(1);                                           \
    _Pragma("unroll")                                                        \
    for (int ut = 0; ut < 4; ++ut)                                           \
      _Pragma("unroll")                                                      \
      for (int lt = 0; lt < 8; ++lt)                                         \
        acc[ut][lt] = __builtin_amdgcn_mfma_f32_16x16x32_bf16(               \
            (R4)[ut], (X8)[lt], acc[ut][lt], 0, 0, 0);                       \
    __builtin_amdgcn_s_setprio(0);                                           \
  }

  short8 fx[2][8], fr[2][4];           // ping-pong carried fragments
  // certify private step 0 (steps 1,2 = 8 loads may remain in flight)
  asm volatile("s_waitcnt vmcnt(8)" ::: "memory");
  READ_FRAGS(0, fx[0], fr[0])

#pragma unroll
  for (int k = 0; k < NSTEP; ++k) {
    const int cb = k & 1, nb = cb ^ 1;
    if (k + 3 < NSTEP) STAGE(k + 3)
    // certify step k+1 (own loads only; per-wave counter)
    if (k + 1 < NSTEP) {
      if (k <= NSTEP - 4)      asm volatile("s_waitcnt vmcnt(8)" ::: "memory");
      else if (k == NSTEP - 3) asm volatile("s_waitcnt vmcnt(4)" ::: "memory");
      else                     asm volatile("s_waitcnt vmcnt(0)" ::: "memory");
      READ_FRAGS(k + 1, fx[nb], fr[nb])
    }
    MFMA32(fr[cb], fx[cb])
  }

#undef READ_FRAGS
#undef MFMA32
#undef STAGE

  // Epilogue: D layout col(l)=lane&15, row(u)=(lane>>4)*4+reg -> lane holds
  // 4 consecutive u at fixed l => float4 store into row-major Z[l][u].
  float* Z = out + SZ_S + SZ_R;
  const int ug = fj << 2;
  float pmax[4][4];                    // [ut][reg]
#pragma unroll
  for (int ut = 0; ut < 4; ++ut)
#pragma unroll
    for (int r = 0; r < 4; ++r) pmax[ut][r] = -INFINITY;

#pragma unroll
  for (int lt = 0; lt < 8; ++lt) {
    const int l = l0 + wl * 128 + lt * 16 + fl;
    if (l < LOUT) {
      float* zrow = Z + ((size_t)n * LOUT + l) * U_ + u0 + wu * 64 + ug;
#pragma unroll
      for (int ut = 0; ut < 4; ++ut) {
        f32x4 v = acc[ut][lt];
        *(f32x4*)(zrow + ut * 16) = v;
#pragma unroll
        for (int r = 0; r < 4; ++r) pmax[ut][r] = fmaxf(pmax[ut][r], v[r]);
      }
    }
  }

  // Max over the frag's 16 cols (l): xor-reduce over lane&15 (fj preserved).
#pragma unroll
  for (int off = 1; off < 16; off <<= 1)
#pragma unroll
    for (int ut = 0; ut < 4; ++ut)
#pragma unroll
      for (int r = 0; r < 4; ++r)
        pmax[ut][r] = fmaxf(pmax[ut][r], __shfl_xor(pmax[ut][r], off));

  if (fl == 0) {                       // lanes fj*16
    const int tn = n / F_;
    float* Sp = out + (size_t)tn * U_ + u0 + wu * 64 + ug;
#pragma unroll
    for (int ut = 0; ut < 4; ++ut)
#pragma unroll
      for (int r = 0; r < 4; ++r)
        atomicMaxF(Sp + ut * 16 + r, pmax[ut][r]);
  }
}

extern "C" void kernel_launch(void* const* d_in, const int* in_sizes, int n_in,
                              void* d_out, int out_size, void* d_ws, size_t ws_size,
                              hipStream_t stream) {
  const float* X       = (const float*)d_in[0];
  const float* P_logit = (const float*)d_in[1];
  const float* Q       = (const float*)d_in[2];
  float* out = (float*)d_out;

  unsigned short* Rt = (unsigned short*)d_ws;            // 240 KB
  unsigned short* Xp = (unsigned short*)((char*)d_ws + 262144);
  // Xp: NIMG*XROWS*24 shorts (~18.6 MB) + slack inside region for the last
  // block's LDS stage over-read (staged-but-never-consumed rows).

  hipLaunchKernelGGL(prep_kernel, dim3(64), dim3(256), 0, stream,
                     P_logit, Q, out, Rt);
  int xthreads = NIMG * XROWS * 12;
  hipLaunchKernelGGL(xconv_kernel, dim3((xthreads + 255) / 256), dim3(256),
                     0, stream, X, (unsigned int*)Xp);
  dim3 grid(2, 4, NIMG);   // u-tiles, l-tiles (256 each), images
  hipLaunchKernelGGL(conv_kernel, grid, dim3(256), 0, stream, Xp, Rt, out);
}